// Round 2
// baseline (292.531 us; speedup 1.0000x reference)
//
#include <hip/hip_runtime.h>

#define NC 5
#define DICE_EPS 1e-7f

typedef unsigned long long u64;
typedef unsigned int u32;

// Workspace layout: 15 counters, each on its own 64B cacheline.
// cnt[c*16]        : den1[c] = count(pred == c)
// cnt[(5+c)*16]    : den2[c] = count(mask == c)
// cnt[(10+c)*16]   : num[c]  = count(pred == c && mask == c)

__global__ __launch_bounds__(256) void dice_hist_kernel(
    const float* __restrict__ pred_f, const int* __restrict__ mask,
    u32* __restrict__ cnt, int n)
{
    u32 den1[NC] = {0, 0, 0, 0, 0};
    u32 den2[NC] = {0, 0, 0, 0, 0};
    u32 num [NC] = {0, 0, 0, 0, 0};

    const int nt  = gridDim.x * blockDim.x;
    const int tid = blockIdx.x * blockDim.x + threadIdx.x;
    const int n4  = n >> 2;

    const float4* __restrict__ p4 = (const float4*)pred_f;
    const int4*   __restrict__ m4 = (const int4*)mask;

    int i = tid;
    while (i < n4) {
        // Packed 8-bit-per-class counters: class c lives in bits [8c, 8c+8).
        // Bin at bits [40,48) is a trash bin for "prediction != label".
        // Flush every <=60 iterations (240 elems) so no 8-bit field overflows.
        u64 A1 = 0, A2 = 0, AN = 0;
        for (int c = 0; c < 60 && i < n4; ++c, i += nt) {
            float4 pf = p4[i];
            int4   mv = m4[i];
            int p0 = (int)pf.x, p1 = (int)pf.y, p2 = (int)pf.z, p3 = (int)pf.w;
            int s0 = p0 << 3, s1 = p1 << 3, s2 = p2 << 3, s3 = p3 << 3;

            A1 += (1ull << s0) + (1ull << s1) + (1ull << s2) + (1ull << s3);
            A2 += (1ull << (mv.x << 3)) + (1ull << (mv.y << 3)) +
                  (1ull << (mv.z << 3)) + (1ull << (mv.w << 3));
            AN += (1ull << (p0 == mv.x ? s0 : 40)) +
                  (1ull << (p1 == mv.y ? s1 : 40)) +
                  (1ull << (p2 == mv.z ? s2 : 40)) +
                  (1ull << (p3 == mv.w ? s3 : 40));
        }
        #pragma unroll
        for (int c = 0; c < NC; ++c) {
            den1[c] += (u32)(A1 >> (8 * c)) & 0xFF;
            den2[c] += (u32)(A2 >> (8 * c)) & 0xFF;
            num [c] += (u32)(AN >> (8 * c)) & 0xFF;
        }
    }

    // scalar tail (n % 4 != 0; not hit for this problem's sizes)
    for (int j = (n4 << 2) + tid; j < n; j += nt) {
        int p = (int)pred_f[j];
        int m = mask[j];
        #pragma unroll
        for (int c = 0; c < NC; ++c) {
            u32 a = (p == c), b = (m == c);
            den1[c] += a;
            den2[c] += b;
            num [c] += a & b;
        }
    }

    // wave-level butterfly reduce (wave = 64 lanes)
    #pragma unroll
    for (int c = 0; c < NC; ++c) {
        #pragma unroll
        for (int off = 32; off > 0; off >>= 1) {
            den1[c] += __shfl_xor(den1[c], off, 64);
            den2[c] += __shfl_xor(den2[c], off, 64);
            num [c] += __shfl_xor(num [c], off, 64);
        }
    }

    __shared__ u32 s_cnt[3 * NC];
    if (threadIdx.x < 3 * NC) s_cnt[threadIdx.x] = 0;
    __syncthreads();

    const int lane = threadIdx.x & 63;
    if (lane == 0) {
        #pragma unroll
        for (int c = 0; c < NC; ++c) {
            atomicAdd(&s_cnt[c],          den1[c]);
            atomicAdd(&s_cnt[NC + c],     den2[c]);
            atomicAdd(&s_cnt[2 * NC + c], num [c]);
        }
    }
    __syncthreads();

    if (threadIdx.x < 3 * NC) {
        atomicAdd(&cnt[threadIdx.x * 16], s_cnt[threadIdx.x]);
    }
}

__global__ void dice_final_kernel(const u32* __restrict__ cnt,
                                  float* __restrict__ out)
{
    if (blockIdx.x == 0 && threadIdx.x == 0) {
        float s = 0.0f;
        #pragma unroll
        for (int c = 0; c < NC; ++c) {
            float d1 = (float)cnt[c * 16];
            float d2 = (float)cnt[(NC + c) * 16];
            float nm = (float)cnt[(2 * NC + c) * 16];
            s += 2.0f * ((nm + DICE_EPS) / (d1 + d2 + DICE_EPS));
        }
        out[0] = s / (float)NC;
    }
}

extern "C" void kernel_launch(void* const* d_in, const int* in_sizes, int n_in,
                              void* d_out, int out_size, void* d_ws, size_t ws_size,
                              hipStream_t stream) {
    const float* pred = (const float*)d_in[0];   // "output": float32 labels
    const int*   mask = (const int*)d_in[1];     // "mask": int32 labels
    const int n = in_sizes[0];                   // 128*512*512 = 33,554,432

    u32* cnt = (u32*)d_ws;
    hipMemsetAsync(d_ws, 0, 3 * NC * 16 * sizeof(u32), stream);

    const int threads = 256;
    const int blocks = 2048;   // 8 blocks/CU -> 32 waves/CU; 16 vec4-iters/thread
    dice_hist_kernel<<<blocks, threads, 0, stream>>>(pred, mask, cnt, n);
    dice_final_kernel<<<1, 64, 0, stream>>>(cnt, (float*)d_out);
}